// Round 1
// baseline (1046.895 us; speedup 1.0000x reference)
//
#include <hip/hip_runtime.h>

// Problem constants: B=2, obj=4, C=256, H=W=48, N=8, HW=2304
#define HH 48
#define WW 48
#define HWP 2304
#define CC 256
#define NB 8

// ---------------- deform-weight transpose: wT[ck][o] = dw[o][ck] -------------
__global__ __launch_bounds__(256) void k_wt(const float* __restrict__ dw,
                                            float* __restrict__ wT) {
    int idx = blockIdx.x * 256 + threadIdx.x;   // 0 .. 589823
    int o  = idx / 2304;
    int ck = idx - o * 2304;
    wT[ck * 256 + o] = dw[idx];                 // read coalesced, write scattered (L2-resident)
}

// ---------------- conv1: feat[b,co,p] = bias + sum_{ci<512,k} w1*concat ------
__global__ __launch_bounds__(256) void k_conv1(
        const float* __restrict__ q, const float* __restrict__ kk,
        const float* __restrict__ w1, const float* __restrict__ b1,
        float* __restrict__ feat) {
    int p   = blockIdx.x * 256 + threadIdx.x;   // 0..2303
    int co0 = blockIdx.y * 8;
    int b   = blockIdx.z;
    int h = p / WW, w = p - h * WW;
    bool up = h > 0, dn = h < HH - 1, lf = w > 0, rt = w < WW - 1;

    float acc[8];
#pragma unroll
    for (int j = 0; j < 8; j++) acc[j] = b1[co0 + j];

    for (int half = 0; half < 2; half++) {
        const float* basec = (half == 0 ? q : kk) + (size_t)b * CC * HWP;
        for (int ci = 0; ci < CC; ci++) {
            const float* c_ = basec + ci * HWP + p;
            float t0 = (up && lf) ? c_[-WW - 1] : 0.f;
            float t1 = up         ? c_[-WW]     : 0.f;
            float t2 = (up && rt) ? c_[-WW + 1] : 0.f;
            float t3 = lf         ? c_[-1]      : 0.f;
            float t4 =              c_[0];
            float t5 = rt         ? c_[1]       : 0.f;
            float t6 = (dn && lf) ? c_[WW - 1]  : 0.f;
            float t7 = dn         ? c_[WW]      : 0.f;
            float t8 = (dn && rt) ? c_[WW + 1]  : 0.f;
#pragma unroll
            for (int j = 0; j < 8; j++) {
                const float* wp = w1 + ((size_t)(co0 + j) * 512 + half * CC + ci) * 9;
                acc[j] += wp[0]*t0 + wp[1]*t1 + wp[2]*t2 + wp[3]*t3 + wp[4]*t4
                        + wp[5]*t5 + wp[6]*t6 + wp[7]*t7 + wp[8]*t8;
            }
        }
    }
    float* outp = feat + ((size_t)b * CC + co0) * HWP + p;
#pragma unroll
    for (int j = 0; j < 8; j++) outp[j * HWP] = acc[j];
}

// ---------------- conv2: off[b,c18,p] (18 channels, per batch) ---------------
__global__ __launch_bounds__(256) void k_conv2(
        const float* __restrict__ feat, const float* __restrict__ w2,
        const float* __restrict__ b2, float* __restrict__ off) {
    int p   = blockIdx.x * 256 + threadIdx.x;
    int c18 = blockIdx.y;
    int b   = blockIdx.z;
    int h = p / WW, w = p - h * WW;
    bool up = h > 0, dn = h < HH - 1, lf = w > 0, rt = w < WW - 1;

    float acc = b2[c18];
    const float* basec = feat + (size_t)b * CC * HWP;
    for (int ci = 0; ci < CC; ci++) {
        const float* c_ = basec + ci * HWP + p;
        float t0 = (up && lf) ? c_[-WW - 1] : 0.f;
        float t1 = up         ? c_[-WW]     : 0.f;
        float t2 = (up && rt) ? c_[-WW + 1] : 0.f;
        float t3 = lf         ? c_[-1]      : 0.f;
        float t4 =              c_[0];
        float t5 = rt         ? c_[1]       : 0.f;
        float t6 = (dn && lf) ? c_[WW - 1]  : 0.f;
        float t7 = dn         ? c_[WW]      : 0.f;
        float t8 = (dn && rt) ? c_[WW + 1]  : 0.f;
        const float* wp = w2 + ((size_t)c18 * CC + ci) * 9;
        acc += wp[0]*t0 + wp[1]*t1 + wp[2]*t2 + wp[3]*t3 + wp[4]*t4
             + wp[5]*t5 + wp[6]*t6 + wp[7]*t7 + wp[8]*t8;
    }
    off[((size_t)b * 18 + c18) * HWP + p] = acc;
}

// ---------------- deform conv + epilogue -------------------------------------
// Block: one n, 16-pixel tile. 256 threads = 64 o-groups (4 o each) x 4 p-groups (4 px each).
// ck = c*9 + k, chunked 288 at a time (32 channels) staged to LDS.
__global__ __launch_bounds__(256) void k_deform(
        const float* __restrict__ value, const float* __restrict__ off,
        const float* __restrict__ wT, const float* __restrict__ db,
        const float* __restrict__ q, float* __restrict__ out) {
    __shared__ float S[288 * 16];      // 18 KB: S[ckl][p]
    __shared__ int   cIdx[4][144];     // bilinear corner indices (clamped)
    __shared__ float cWt[4][144];      // bilinear corner weights (0 if invalid)

    int tid   = threadIdx.x;
    int n     = blockIdx.y;
    int b     = n >> 2;
    int pbase = blockIdx.x * 16;

    if (tid < 144) {
        int k = tid / 16, p = tid - k * 16;
        int pp = pbase + p;
        int h = pp / WW, w = pp - h * WW;
        float dy = off[((size_t)b * 18 + 2 * k) * HWP + pp];
        float dx = off[((size_t)b * 18 + 2 * k + 1) * HWP + pp];
        float py = dy + (float)h + (float)(k / 3 - 1);
        float px = dx + (float)w + (float)(k % 3 - 1);
        float y0f = floorf(py), x0f = floorf(px);
        int y0 = (int)y0f, x0 = (int)x0f;
        float fy = py - y0f, fx = px - x0f;
        bool y0ok = (y0 >= 0 && y0 < HH), y1ok = (y0 + 1 >= 0 && y0 + 1 < HH);
        bool x0ok = (x0 >= 0 && x0 < WW), x1ok = (x0 + 1 >= 0 && x0 + 1 < WW);
        int y0c = min(max(y0, 0), HH - 1), y1c = min(max(y0 + 1, 0), HH - 1);
        int x0c = min(max(x0, 0), WW - 1), x1c = min(max(x0 + 1, 0), WW - 1);
        cIdx[0][tid] = y0c * WW + x0c;  cWt[0][tid] = (y0ok && x0ok) ? (1.f - fy) * (1.f - fx) : 0.f;
        cIdx[1][tid] = y0c * WW + x1c;  cWt[1][tid] = (y0ok && x1ok) ? (1.f - fy) * fx         : 0.f;
        cIdx[2][tid] = y1c * WW + x0c;  cWt[2][tid] = (y1ok && x0ok) ? fy * (1.f - fx)         : 0.f;
        cIdx[3][tid] = y1c * WW + x1c;  cWt[3][tid] = (y1ok && x1ok) ? fy * fx                 : 0.f;
    }
    __syncthreads();

    float acc[4][4] = {};               // [pixel][o]
    int ot = tid & 63, pt = tid >> 6;
    int o0 = ot * 4;
    const float* xbase = value + (size_t)n * CC * HWP;

    for (int cc = 0; cc < 8; cc++) {
        int c0 = cc * 32;
        // stage S[ckl][p] for ck in [c0*9, c0*9+288)
        for (int i = tid; i < 288 * 16; i += 256) {
            int p = i & 15, ckl = i >> 4;
            int k = ckl % 9, cl = ckl / 9;
            const float* xc = xbase + (size_t)(c0 + cl) * HWP;
            int ci = k * 16 + p;
            S[i] = cWt[0][ci] * xc[cIdx[0][ci]] + cWt[1][ci] * xc[cIdx[1][ci]]
                 + cWt[2][ci] * xc[cIdx[2][ci]] + cWt[3][ci] * xc[cIdx[3][ci]];
        }
        __syncthreads();
        const float* wrow = wT + (size_t)(c0 * 9) * 256 + o0;
#pragma unroll 4
        for (int ckl = 0; ckl < 288; ckl++) {
            float4 wv = *(const float4*)(wrow + (size_t)ckl * 256);   // 4 o, coalesced across lanes
            float4 sv = *(const float4*)(&S[ckl * 16 + pt * 4]);      // 4 px, wave-broadcast
            acc[0][0] += sv.x * wv.x; acc[0][1] += sv.x * wv.y; acc[0][2] += sv.x * wv.z; acc[0][3] += sv.x * wv.w;
            acc[1][0] += sv.y * wv.x; acc[1][1] += sv.y * wv.y; acc[1][2] += sv.y * wv.z; acc[1][3] += sv.y * wv.w;
            acc[2][0] += sv.z * wv.x; acc[2][1] += sv.z * wv.y; acc[2][2] += sv.z * wv.z; acc[2][3] += sv.z * wv.w;
            acc[3][0] += sv.w * wv.x; acc[3][1] += sv.w * wv.y; acc[3][2] += sv.w * wv.z; acc[3][3] += sv.w * wv.w;
        }
        __syncthreads();
    }

    // epilogue: out[p, n, o] = acc + deform_b[o] + query[b, o, p]
    float bj[4];
#pragma unroll
    for (int j = 0; j < 4; j++) bj[j] = db[o0 + j];
#pragma unroll
    for (int pi = 0; pi < 4; pi++) {
        int pp = pbase + pt * 4 + pi;
        float4 r;
        r.x = acc[pi][0] + bj[0] + q[((size_t)b * CC + o0 + 0) * HWP + pp];
        r.y = acc[pi][1] + bj[1] + q[((size_t)b * CC + o0 + 1) * HWP + pp];
        r.z = acc[pi][2] + bj[2] + q[((size_t)b * CC + o0 + 2) * HWP + pp];
        r.w = acc[pi][3] + bj[3] + q[((size_t)b * CC + o0 + 3) * HWP + pp];
        *(float4*)(out + (size_t)pp * (NB * CC) + n * CC + o0) = r;
    }
}

extern "C" void kernel_launch(void* const* d_in, const int* in_sizes, int n_in,
                              void* d_out, int out_size, void* d_ws, size_t ws_size,
                              hipStream_t stream) {
    const float* q  = (const float*)d_in[0];
    const float* k  = (const float*)d_in[1];
    const float* v  = (const float*)d_in[2];
    const float* w1 = (const float*)d_in[3];
    const float* b1 = (const float*)d_in[4];
    const float* w2 = (const float*)d_in[5];
    const float* b2 = (const float*)d_in[6];
    const float* dw = (const float*)d_in[7];
    const float* db = (const float*)d_in[8];
    float* out = (float*)d_out;

    // workspace layout (floats): feat [2*256*2304] | off [2*18*2304] | wT [2304*256]
    float* feat = (float*)d_ws;
    float* off  = feat + 2 * 256 * 2304;      // 1,179,648
    float* wT   = off  + 2 * 18 * 2304;       // + 82,944
    // total 1,852,416 floats = 7.4 MB

    hipLaunchKernelGGL(k_wt,     dim3(2304),      dim3(256), 0, stream, dw, wT);
    hipLaunchKernelGGL(k_conv1,  dim3(9, 32, 2),  dim3(256), 0, stream, q, k, w1, b1, feat);
    hipLaunchKernelGGL(k_conv2,  dim3(9, 18, 2),  dim3(256), 0, stream, feat, w2, b2, off);
    hipLaunchKernelGGL(k_deform, dim3(144, 8),    dim3(256), 0, stream, v, off, wT, db, q, out);
}

// Round 2
// 795.134 us; speedup vs baseline: 1.3166x; 1.3166x over previous
//
#include <hip/hip_runtime.h>

// Problem constants: B=2, obj=4, C=256, H=W=48, N=8, HW=2304
#define HH 48
#define WW 48
#define HWP 2304
#define CC 256
#define NB 8

typedef __attribute__((ext_vector_type(8))) short short8;   // 8 x bf16 = 4 VGPR
typedef __attribute__((ext_vector_type(4))) float floatx4;  // MFMA C/D frag

static __device__ __forceinline__ unsigned short f2bf(float f) {
    union { float f; unsigned u; } v; v.f = f;
    unsigned r = v.u + 0x7fffu + ((v.u >> 16) & 1u);        // RNE
    return (unsigned short)(r >> 16);
}

// ---------------- deform-weight cast: wTl[o][ck] = bf16(dw[o][ck]) ----------
__global__ __launch_bounds__(256) void k_wt(const float* __restrict__ dw,
                                            unsigned short* __restrict__ wTl) {
    int idx = blockIdx.x * 256 + threadIdx.x;   // 0 .. 589823
    wTl[idx] = f2bf(dw[idx]);
}

// ---------------- conv1: feat[b,co,p] (unchanged from R1, known-correct) ----
__global__ __launch_bounds__(256) void k_conv1(
        const float* __restrict__ q, const float* __restrict__ kk,
        const float* __restrict__ w1, const float* __restrict__ b1,
        float* __restrict__ feat) {
    int p   = blockIdx.x * 256 + threadIdx.x;
    int co0 = blockIdx.y * 8;
    int b   = blockIdx.z;
    int h = p / WW, w = p - h * WW;
    bool up = h > 0, dn = h < HH - 1, lf = w > 0, rt = w < WW - 1;

    float acc[8];
#pragma unroll
    for (int j = 0; j < 8; j++) acc[j] = b1[co0 + j];

    for (int half = 0; half < 2; half++) {
        const float* basec = (half == 0 ? q : kk) + (size_t)b * CC * HWP;
        for (int ci = 0; ci < CC; ci++) {
            const float* c_ = basec + ci * HWP + p;
            float t0 = (up && lf) ? c_[-WW - 1] : 0.f;
            float t1 = up         ? c_[-WW]     : 0.f;
            float t2 = (up && rt) ? c_[-WW + 1] : 0.f;
            float t3 = lf         ? c_[-1]      : 0.f;
            float t4 =              c_[0];
            float t5 = rt         ? c_[1]       : 0.f;
            float t6 = (dn && lf) ? c_[WW - 1]  : 0.f;
            float t7 = dn         ? c_[WW]      : 0.f;
            float t8 = (dn && rt) ? c_[WW + 1]  : 0.f;
#pragma unroll
            for (int j = 0; j < 8; j++) {
                const float* wp = w1 + ((size_t)(co0 + j) * 512 + half * CC + ci) * 9;
                acc[j] += wp[0]*t0 + wp[1]*t1 + wp[2]*t2 + wp[3]*t3 + wp[4]*t4
                        + wp[5]*t5 + wp[6]*t6 + wp[7]*t7 + wp[8]*t8;
            }
        }
    }
    float* outp = feat + ((size_t)b * CC + co0) * HWP + p;
#pragma unroll
    for (int j = 0; j < 8; j++) outp[j * HWP] = acc[j];
}

// ---------------- conv2: off[b,c18,p] (unchanged from R1) -------------------
__global__ __launch_bounds__(256) void k_conv2(
        const float* __restrict__ feat, const float* __restrict__ w2,
        const float* __restrict__ b2, float* __restrict__ off) {
    int p   = blockIdx.x * 256 + threadIdx.x;
    int c18 = blockIdx.y;
    int b   = blockIdx.z;
    int h = p / WW, w = p - h * WW;
    bool up = h > 0, dn = h < HH - 1, lf = w > 0, rt = w < WW - 1;

    float acc = b2[c18];
    const float* basec = feat + (size_t)b * CC * HWP;
    for (int ci = 0; ci < CC; ci++) {
        const float* c_ = basec + ci * HWP + p;
        float t0 = (up && lf) ? c_[-WW - 1] : 0.f;
        float t1 = up         ? c_[-WW]     : 0.f;
        float t2 = (up && rt) ? c_[-WW + 1] : 0.f;
        float t3 = lf         ? c_[-1]      : 0.f;
        float t4 =              c_[0];
        float t5 = rt         ? c_[1]       : 0.f;
        float t6 = (dn && lf) ? c_[WW - 1]  : 0.f;
        float t7 = dn         ? c_[WW]      : 0.f;
        float t8 = (dn && rt) ? c_[WW + 1]  : 0.f;
        const float* wp = w2 + ((size_t)c18 * CC + ci) * 9;
        acc += wp[0]*t0 + wp[1]*t1 + wp[2]*t2 + wp[3]*t3 + wp[4]*t4
             + wp[5]*t5 + wp[6]*t6 + wp[7]*t7 + wp[8]*t8;
    }
    off[((size_t)b * 18 + c18) * HWP + p] = acc;
}

// ---------------- bilinear corner setup (per tap, per pixel) ----------------
static __device__ __forceinline__ void bilin(const float* __restrict__ off,
        int b, int tap, int pp, int h, int w, int* idx, float* wt) {
    float dy = off[((size_t)b * 18 + 2 * tap) * HWP + pp];
    float dx = off[((size_t)b * 18 + 2 * tap + 1) * HWP + pp];
    float py = dy + (float)h + (float)(tap / 3 - 1);
    float px = dx + (float)w + (float)(tap % 3 - 1);
    float y0f = floorf(py), x0f = floorf(px);
    int y0 = (int)y0f, x0 = (int)x0f;
    float fy = py - y0f, fx = px - x0f;
    bool y0ok = (y0 >= 0) & (y0 < HH), y1ok = (y0 >= -1) & (y0 < HH - 1);
    bool x0ok = (x0 >= 0) & (x0 < WW), x1ok = (x0 >= -1) & (x0 < WW - 1);
    int y0c = min(max(y0, 0), HH - 1), y1c = min(max(y0 + 1, 0), HH - 1);
    int x0c = min(max(x0, 0), WW - 1), x1c = min(max(x0 + 1, 0), WW - 1);
    idx[0] = y0c * WW + x0c; wt[0] = (y0ok && x0ok) ? (1.f - fy) * (1.f - fx) : 0.f;
    idx[1] = y0c * WW + x1c; wt[1] = (y0ok && x1ok) ? (1.f - fy) * fx         : 0.f;
    idx[2] = y1c * WW + x0c; wt[2] = (y1ok && x0ok) ? fy * (1.f - fx)         : 0.f;
    idx[3] = y1c * WW + x1c; wt[3] = (y1ok && x1ok) ? fy * fx                 : 0.f;
}

// ---------------- deform conv via bf16 MFMA + epilogue ----------------------
// Block = one n x 32 pixels. 4 waves, each computing 64 o x 32 p via
// 16x16x32_bf16 MFMA (4 m-tiles x 2 n-tiles). K = 2304 (ck = c*9+tap),
// chunked 288 (32 channels). A (=wTl, bf16, [o][ck] k-contiguous) loaded
// straight from global (L2-resident); B (=bilinear samples S[p][k]) staged
// in LDS, row padded 288->296 so 16-lane ds_read_b128 is 2-way max (free).
__global__ __launch_bounds__(256) void k_deform(
        const float* __restrict__ value, const float* __restrict__ off,
        const unsigned short* __restrict__ wTl, const float* __restrict__ db,
        const float* __restrict__ q, float* __restrict__ out) {
    __shared__ __align__(16) unsigned short Sl[32 * 296];   // 18.5 KB

    const int tid   = threadIdx.x;
    const int n     = blockIdx.y;
    const int b     = n >> 2;
    const int pbase = blockIdx.x * 32;

    // per-thread (tap, pixel) bilinear corners, held in registers all kernel
    const int p  = tid & 31;
    const int pp = pbase + p;
    const int h  = pp / WW, w = pp - (pp / WW) * WW;
    const int tapA = tid >> 5;                      // 0..7
    int iA[4]; float wA[4];
    bilin(off, b, tapA, pp, h, w, iA, wA);
    int iB[4]; float wB[4];
    if (tid < 32) bilin(off, b, 8, pp, h, w, iB, wB);   // tap 8 on wave 0

    const int lane = tid & 63;
    const int wv   = tid >> 6;                      // wave 0..3 -> o block
    const int lo   = lane & 15;
    const int quad = lane >> 4;

    floatx4 acc[4][2];
#pragma unroll
    for (int mt = 0; mt < 4; mt++)
#pragma unroll
        for (int nt = 0; nt < 2; nt++) acc[mt][nt] = (floatx4)0.f;

    const float* xn = value + (size_t)n * CC * HWP;
    const unsigned short* aBase = wTl + (size_t)(wv * 64 + lo) * HWP + quad * 8;
    const unsigned short* bBase = Sl + lo * 296 + quad * 8;

    for (int cc8 = 0; cc8 < 8; cc8++) {             // 8 chunks of 32 channels
        // ---- stage S[p][cl*9+tap] = bilinear sample, bf16 ----
        const float* xc = xn + (size_t)cc8 * 32 * HWP;
        {
            unsigned short* srow = Sl + p * 296 + tapA;
#pragma unroll 4
            for (int cl = 0; cl < 32; cl++) {
                const float* x_ = xc + cl * HWP;
                float s = wA[0] * x_[iA[0]] + wA[1] * x_[iA[1]]
                        + wA[2] * x_[iA[2]] + wA[3] * x_[iA[3]];
                srow[cl * 9] = f2bf(s);
            }
        }
        if (tid < 32) {
            unsigned short* srow = Sl + p * 296 + 8;
#pragma unroll 4
            for (int cl = 0; cl < 32; cl++) {
                const float* x_ = xc + cl * HWP;
                float s = wB[0] * x_[iB[0]] + wB[1] * x_[iB[1]]
                        + wB[2] * x_[iB[2]] + wB[3] * x_[iB[3]];
                srow[cl * 9] = f2bf(s);
            }
        }
        __syncthreads();

        // ---- GEMM: 9 K-steps of 32 over this chunk ----
        const unsigned short* aC = aBase + cc8 * 288;
#pragma unroll
        for (int ks = 0; ks < 9; ks++) {
            short8 a0 = *(const short8*)(aC + ks * 32);
            short8 a1 = *(const short8*)(aC + ks * 32 + 16 * HWP);
            short8 a2 = *(const short8*)(aC + ks * 32 + 32 * HWP);
            short8 a3 = *(const short8*)(aC + ks * 32 + 48 * HWP);
            short8 b0 = *(const short8*)(bBase + ks * 32);
            short8 b1 = *(const short8*)(bBase + ks * 32 + 16 * 296);
            acc[0][0] = __builtin_amdgcn_mfma_f32_16x16x32_bf16(a0, b0, acc[0][0], 0, 0, 0);
            acc[1][0] = __builtin_amdgcn_mfma_f32_16x16x32_bf16(a1, b0, acc[1][0], 0, 0, 0);
            acc[2][0] = __builtin_amdgcn_mfma_f32_16x16x32_bf16(a2, b0, acc[2][0], 0, 0, 0);
            acc[3][0] = __builtin_amdgcn_mfma_f32_16x16x32_bf16(a3, b0, acc[3][0], 0, 0, 0);
            acc[0][1] = __builtin_amdgcn_mfma_f32_16x16x32_bf16(a0, b1, acc[0][1], 0, 0, 0);
            acc[1][1] = __builtin_amdgcn_mfma_f32_16x16x32_bf16(a1, b1, acc[1][1], 0, 0, 0);
            acc[2][1] = __builtin_amdgcn_mfma_f32_16x16x32_bf16(a2, b1, acc[2][1], 0, 0, 0);
            acc[3][1] = __builtin_amdgcn_mfma_f32_16x16x32_bf16(a3, b1, acc[3][1], 0, 0, 0);
        }
        __syncthreads();
    }

    // ---- epilogue: out[p, n, o] = acc + db[o] + query[b, o, p] ----
    // C/D layout: col(n-dim)=lane&15, row(m-dim)=quad*4+reg  [m89/m91-verified]
#pragma unroll
    for (int mt = 0; mt < 4; mt++) {
        int o = wv * 64 + mt * 16 + quad * 4;
        float d0 = db[o], d1 = db[o + 1], d2 = db[o + 2], d3 = db[o + 3];
#pragma unroll
        for (int nt = 0; nt < 2; nt++) {
            int pq = pbase + nt * 16 + lo;
            floatx4 r = acc[mt][nt];
            r[0] += d0 + q[((size_t)b * CC + o + 0) * HWP + pq];
            r[1] += d1 + q[((size_t)b * CC + o + 1) * HWP + pq];
            r[2] += d2 + q[((size_t)b * CC + o + 2) * HWP + pq];
            r[3] += d3 + q[((size_t)b * CC + o + 3) * HWP + pq];
            *(floatx4*)(out + (size_t)pq * (NB * CC) + n * CC + o) = r;
        }
    }
}

extern "C" void kernel_launch(void* const* d_in, const int* in_sizes, int n_in,
                              void* d_out, int out_size, void* d_ws, size_t ws_size,
                              hipStream_t stream) {
    const float* q  = (const float*)d_in[0];
    const float* k  = (const float*)d_in[1];
    const float* v  = (const float*)d_in[2];
    const float* w1 = (const float*)d_in[3];
    const float* b1 = (const float*)d_in[4];
    const float* w2 = (const float*)d_in[5];
    const float* b2 = (const float*)d_in[6];
    const float* dw = (const float*)d_in[7];
    const float* db = (const float*)d_in[8];
    float* out = (float*)d_out;

    // ws layout (floats): feat [2*256*2304] | off [2*18*2304] | wTl bf16 [256*2304]
    float* feat = (float*)d_ws;
    float* off  = feat + 2 * 256 * 2304;                 // 1,179,648
    unsigned short* wTl = (unsigned short*)(off + 2 * 18 * 2304);  // 16B-aligned

    hipLaunchKernelGGL(k_wt,     dim3(2304),     dim3(256), 0, stream, dw, wTl);
    hipLaunchKernelGGL(k_conv1,  dim3(9, 32, 2), dim3(256), 0, stream, q, k, w1, b1, feat);
    hipLaunchKernelGGL(k_conv2,  dim3(9, 18, 2), dim3(256), 0, stream, feat, w2, b2, off);
    hipLaunchKernelGGL(k_deform, dim3(72, 8),    dim3(256), 0, stream, v, off, wTl, db, q, out);
}

// Round 3
// 524.852 us; speedup vs baseline: 1.9947x; 1.5150x over previous
//
#include <hip/hip_runtime.h>

// Problem constants: B=2, obj=4, C=256, H=W=48, N=8, HW=2304
#define HH 48
#define WW 48
#define HWP 2304
#define CC 256
#define NB 8

typedef __attribute__((ext_vector_type(8))) short short8;   // 8 x bf16 = 4 VGPR
typedef __attribute__((ext_vector_type(4))) float floatx4;  // MFMA C/D frag

static __device__ __forceinline__ unsigned short f2bf(float f) {
    union { float f; unsigned u; } v; v.f = f;
    unsigned r = v.u + 0x7fffu + ((v.u >> 16) & 1u);        // RNE
    return (unsigned short)(r >> 16);
}

// ---------------- generic fp32 -> bf16 cast ---------------------------------
__global__ __launch_bounds__(256) void k_cast(const float* __restrict__ src,
                                              unsigned short* __restrict__ dst) {
    int idx = blockIdx.x * 256 + threadIdx.x;
    dst[idx] = f2bf(src[idx]);
}

// ---------------- feat bias init (conv1 epilogue atomically adds) -----------
__global__ __launch_bounds__(256) void k_binit(const float* __restrict__ b1,
                                               float* __restrict__ feat) {
    int idx = blockIdx.x * 256 + threadIdx.x;   // 0 .. 1,179,647
    int o = (idx / HWP) & (CC - 1);
    feat[idx] = b1[o];
}

// ---------------- conv1 via bf16 MFMA: feat[b,o,p] += sum w1*concat ---------
// GEMM: M=256 (o), N=2304 px (x2 b), K=4608 (ci*9+tap), split-K over grid.z
// (kh=0 -> q channels, kh=1 -> k channels). Block = 32 px, 4 waves x 64 o.
// A = w1b (bf16, [o][ci*9+tap], k-contiguous) straight from L2.
// B = im2col staged in LDS, row padded 288->296.
__global__ __launch_bounds__(256) void k_conv1(
        const float* __restrict__ q, const float* __restrict__ kk,
        const unsigned short* __restrict__ w1b, float* __restrict__ feat) {
    __shared__ __align__(16) unsigned short Sl[32 * 296];   // 18.5 KB

    const int tid   = threadIdx.x;
    const int pbase = blockIdx.x * 32;
    const int b     = blockIdx.y;
    const int kh    = blockIdx.z;                  // K-half

    const int p  = tid & 31;
    const int pp = pbase + p;
    const int h  = pp / WW, w = pp - (pp / WW) * WW;

    // per-thread tap shift + validity (tap = tid>>5 for 0..7; tap 8 on tid<32)
    const int tapA = tid >> 5;
    const int dyA = tapA / 3 - 1, dxA = tapA % 3 - 1;
    const bool vA = (h + dyA >= 0) && (h + dyA < HH) && (w + dxA >= 0) && (w + dxA < WW);
    const int   saA = vA ? pp + dyA * WW + dxA : pp;
    const float vmA = vA ? 1.f : 0.f;
    const bool v8 = (h + 1 < HH) && (w + 1 < WW);
    const int   sa8 = v8 ? pp + WW + 1 : pp;
    const float vm8 = v8 ? 1.f : 0.f;

    const float* src = (kh == 0 ? q : kk) + (size_t)b * CC * HWP;

    const int lane = tid & 63;
    const int wv   = tid >> 6;
    const int lo   = lane & 15;
    const int quad = lane >> 4;

    floatx4 acc[4][2];
#pragma unroll
    for (int mt = 0; mt < 4; mt++)
#pragma unroll
        for (int nt = 0; nt < 2; nt++) acc[mt][nt] = (floatx4)0.f;

    const unsigned short* aBase = w1b + (size_t)(wv * 64 + lo) * 4608 + kh * 2304 + quad * 8;
    const unsigned short* bBase = Sl + lo * 296 + quad * 8;

    for (int cc8 = 0; cc8 < 8; cc8++) {            // 8 chunks of 32 channels
        const float* xc = src + (size_t)cc8 * 32 * HWP;
        {
            unsigned short* srow = Sl + p * 296 + tapA;
#pragma unroll 4
            for (int cl = 0; cl < 32; cl++)
                srow[cl * 9] = f2bf(xc[cl * HWP + saA] * vmA);
        }
        if (tid < 32) {
            unsigned short* sr8 = Sl + p * 296 + 8;
#pragma unroll 4
            for (int cl = 0; cl < 32; cl++)
                sr8[cl * 9] = f2bf(xc[cl * HWP + sa8] * vm8);
        }
        __syncthreads();

        const unsigned short* aC = aBase + cc8 * 288;
#pragma unroll
        for (int ks = 0; ks < 9; ks++) {
            short8 a0 = *(const short8*)(aC + ks * 32);
            short8 a1 = *(const short8*)(aC + ks * 32 + 16 * 4608);
            short8 a2 = *(const short8*)(aC + ks * 32 + 32 * 4608);
            short8 a3 = *(const short8*)(aC + ks * 32 + 48 * 4608);
            short8 b0 = *(const short8*)(bBase + ks * 32);
            short8 b1 = *(const short8*)(bBase + ks * 32 + 16 * 296);
            acc[0][0] = __builtin_amdgcn_mfma_f32_16x16x32_bf16(a0, b0, acc[0][0], 0, 0, 0);
            acc[1][0] = __builtin_amdgcn_mfma_f32_16x16x32_bf16(a1, b0, acc[1][0], 0, 0, 0);
            acc[2][0] = __builtin_amdgcn_mfma_f32_16x16x32_bf16(a2, b0, acc[2][0], 0, 0, 0);
            acc[3][0] = __builtin_amdgcn_mfma_f32_16x16x32_bf16(a3, b0, acc[3][0], 0, 0, 0);
            acc[0][1] = __builtin_amdgcn_mfma_f32_16x16x32_bf16(a0, b1, acc[0][1], 0, 0, 0);
            acc[1][1] = __builtin_amdgcn_mfma_f32_16x16x32_bf16(a1, b1, acc[1][1], 0, 0, 0);
            acc[2][1] = __builtin_amdgcn_mfma_f32_16x16x32_bf16(a2, b1, acc[2][1], 0, 0, 0);
            acc[3][1] = __builtin_amdgcn_mfma_f32_16x16x32_bf16(a3, b1, acc[3][1], 0, 0, 0);
        }
        __syncthreads();
    }

    // epilogue: feat[b][o][pq] += acc  (split-K partial; bias pre-initialized)
#pragma unroll
    for (int mt = 0; mt < 4; mt++) {
        int o = wv * 64 + mt * 16 + quad * 4;
#pragma unroll
        for (int nt = 0; nt < 2; nt++) {
            int pq = pbase + nt * 16 + lo;
            float* fp = feat + ((size_t)b * CC + o) * HWP + pq;
            atomicAdd(fp,            acc[mt][nt][0]);
            atomicAdd(fp + HWP,      acc[mt][nt][1]);
            atomicAdd(fp + 2 * HWP,  acc[mt][nt][2]);
            atomicAdd(fp + 3 * HWP,  acc[mt][nt][3]);
        }
    }
}

// ---------------- conv2: off[b,c18,p] (unchanged) ---------------------------
__global__ __launch_bounds__(256) void k_conv2(
        const float* __restrict__ feat, const float* __restrict__ w2,
        const float* __restrict__ b2, float* __restrict__ off) {
    int p   = blockIdx.x * 256 + threadIdx.x;
    int c18 = blockIdx.y;
    int b   = blockIdx.z;
    int h = p / WW, w = p - h * WW;
    bool up = h > 0, dn = h < HH - 1, lf = w > 0, rt = w < WW - 1;

    float acc = b2[c18];
    const float* basec = feat + (size_t)b * CC * HWP;
    for (int ci = 0; ci < CC; ci++) {
        const float* c_ = basec + ci * HWP + p;
        float t0 = (up && lf) ? c_[-WW - 1] : 0.f;
        float t1 = up         ? c_[-WW]     : 0.f;
        float t2 = (up && rt) ? c_[-WW + 1] : 0.f;
        float t3 = lf         ? c_[-1]      : 0.f;
        float t4 =              c_[0];
        float t5 = rt         ? c_[1]       : 0.f;
        float t6 = (dn && lf) ? c_[WW - 1]  : 0.f;
        float t7 = dn         ? c_[WW]      : 0.f;
        float t8 = (dn && rt) ? c_[WW + 1]  : 0.f;
        const float* wp = w2 + ((size_t)c18 * CC + ci) * 9;
        acc += wp[0]*t0 + wp[1]*t1 + wp[2]*t2 + wp[3]*t3 + wp[4]*t4
             + wp[5]*t5 + wp[6]*t6 + wp[7]*t7 + wp[8]*t8;
    }
    off[((size_t)b * 18 + c18) * HWP + p] = acc;
}

// ---------------- bilinear corner setup -------------------------------------
static __device__ __forceinline__ void bilin(const float* __restrict__ off,
        int b, int tap, int pp, int h, int w, int* idx, float* wt) {
    float dy = off[((size_t)b * 18 + 2 * tap) * HWP + pp];
    float dx = off[((size_t)b * 18 + 2 * tap + 1) * HWP + pp];
    float py = dy + (float)h + (float)(tap / 3 - 1);
    float px = dx + (float)w + (float)(tap % 3 - 1);
    float y0f = floorf(py), x0f = floorf(px);
    int y0 = (int)y0f, x0 = (int)x0f;
    float fy = py - y0f, fx = px - x0f;
    bool y0ok = (y0 >= 0) & (y0 < HH), y1ok = (y0 >= -1) & (y0 < HH - 1);
    bool x0ok = (x0 >= 0) & (x0 < WW), x1ok = (x0 >= -1) & (x0 < WW - 1);
    int y0c = min(max(y0, 0), HH - 1), y1c = min(max(y0 + 1, 0), HH - 1);
    int x0c = min(max(x0, 0), WW - 1), x1c = min(max(x0 + 1, 0), WW - 1);
    idx[0] = y0c * WW + x0c; wt[0] = (y0ok && x0ok) ? (1.f - fy) * (1.f - fx) : 0.f;
    idx[1] = y0c * WW + x1c; wt[1] = (y0ok && x1ok) ? (1.f - fy) * fx         : 0.f;
    idx[2] = y1c * WW + x0c; wt[2] = (y1ok && x0ok) ? fy * (1.f - fx)         : 0.f;
    idx[3] = y1c * WW + x1c; wt[3] = (y1ok && x1ok) ? fy * fx                 : 0.f;
}

// ---------------- deform conv via bf16 MFMA + epilogue (unchanged R2) -------
__global__ __launch_bounds__(256) void k_deform(
        const float* __restrict__ value, const float* __restrict__ off,
        const unsigned short* __restrict__ wTl, const float* __restrict__ db,
        const float* __restrict__ q, float* __restrict__ out) {
    __shared__ __align__(16) unsigned short Sl[32 * 296];   // 18.5 KB

    const int tid   = threadIdx.x;
    const int n     = blockIdx.y;
    const int b     = n >> 2;
    const int pbase = blockIdx.x * 32;

    const int p  = tid & 31;
    const int pp = pbase + p;
    const int h  = pp / WW, w = pp - (pp / WW) * WW;
    const int tapA = tid >> 5;                      // 0..7
    int iA[4]; float wA[4];
    bilin(off, b, tapA, pp, h, w, iA, wA);
    int iB[4]; float wB[4];
    if (tid < 32) bilin(off, b, 8, pp, h, w, iB, wB);

    const int lane = tid & 63;
    const int wv   = tid >> 6;
    const int lo   = lane & 15;
    const int quad = lane >> 4;

    floatx4 acc[4][2];
#pragma unroll
    for (int mt = 0; mt < 4; mt++)
#pragma unroll
        for (int nt = 0; nt < 2; nt++) acc[mt][nt] = (floatx4)0.f;

    const float* xn = value + (size_t)n * CC * HWP;
    const unsigned short* aBase = wTl + (size_t)(wv * 64 + lo) * HWP + quad * 8;
    const unsigned short* bBase = Sl + lo * 296 + quad * 8;

    for (int cc8 = 0; cc8 < 8; cc8++) {
        const float* xc = xn + (size_t)cc8 * 32 * HWP;
        {
            unsigned short* srow = Sl + p * 296 + tapA;
#pragma unroll 4
            for (int cl = 0; cl < 32; cl++) {
                const float* x_ = xc + cl * HWP;
                float s = wA[0] * x_[iA[0]] + wA[1] * x_[iA[1]]
                        + wA[2] * x_[iA[2]] + wA[3] * x_[iA[3]];
                srow[cl * 9] = f2bf(s);
            }
        }
        if (tid < 32) {
            unsigned short* srow = Sl + p * 296 + 8;
#pragma unroll 4
            for (int cl = 0; cl < 32; cl++) {
                const float* x_ = xc + cl * HWP;
                float s = wB[0] * x_[iB[0]] + wB[1] * x_[iB[1]]
                        + wB[2] * x_[iB[2]] + wB[3] * x_[iB[3]];
                srow[cl * 9] = f2bf(s);
            }
        }
        __syncthreads();

        const unsigned short* aC = aBase + cc8 * 288;
#pragma unroll
        for (int ks = 0; ks < 9; ks++) {
            short8 a0 = *(const short8*)(aC + ks * 32);
            short8 a1 = *(const short8*)(aC + ks * 32 + 16 * HWP);
            short8 a2 = *(const short8*)(aC + ks * 32 + 32 * HWP);
            short8 a3 = *(const short8*)(aC + ks * 32 + 48 * HWP);
            short8 b0 = *(const short8*)(bBase + ks * 32);
            short8 b1 = *(const short8*)(bBase + ks * 32 + 16 * 296);
            acc[0][0] = __builtin_amdgcn_mfma_f32_16x16x32_bf16(a0, b0, acc[0][0], 0, 0, 0);
            acc[1][0] = __builtin_amdgcn_mfma_f32_16x16x32_bf16(a1, b0, acc[1][0], 0, 0, 0);
            acc[2][0] = __builtin_amdgcn_mfma_f32_16x16x32_bf16(a2, b0, acc[2][0], 0, 0, 0);
            acc[3][0] = __builtin_amdgcn_mfma_f32_16x16x32_bf16(a3, b0, acc[3][0], 0, 0, 0);
            acc[0][1] = __builtin_amdgcn_mfma_f32_16x16x32_bf16(a0, b1, acc[0][1], 0, 0, 0);
            acc[1][1] = __builtin_amdgcn_mfma_f32_16x16x32_bf16(a1, b1, acc[1][1], 0, 0, 0);
            acc[2][1] = __builtin_amdgcn_mfma_f32_16x16x32_bf16(a2, b1, acc[2][1], 0, 0, 0);
            acc[3][1] = __builtin_amdgcn_mfma_f32_16x16x32_bf16(a3, b1, acc[3][1], 0, 0, 0);
        }
        __syncthreads();
    }

#pragma unroll
    for (int mt = 0; mt < 4; mt++) {
        int o = wv * 64 + mt * 16 + quad * 4;
        float d0 = db[o], d1 = db[o + 1], d2 = db[o + 2], d3 = db[o + 3];
#pragma unroll
        for (int nt = 0; nt < 2; nt++) {
            int pq = pbase + nt * 16 + lo;
            floatx4 r = acc[mt][nt];
            r[0] += d0 + q[((size_t)b * CC + o + 0) * HWP + pq];
            r[1] += d1 + q[((size_t)b * CC + o + 1) * HWP + pq];
            r[2] += d2 + q[((size_t)b * CC + o + 2) * HWP + pq];
            r[3] += d3 + q[((size_t)b * CC + o + 3) * HWP + pq];
            *(floatx4*)(out + (size_t)pq * (NB * CC) + n * CC + o) = r;
        }
    }
}

extern "C" void kernel_launch(void* const* d_in, const int* in_sizes, int n_in,
                              void* d_out, int out_size, void* d_ws, size_t ws_size,
                              hipStream_t stream) {
    const float* q  = (const float*)d_in[0];
    const float* k  = (const float*)d_in[1];
    const float* v  = (const float*)d_in[2];
    const float* w1 = (const float*)d_in[3];
    const float* b1 = (const float*)d_in[4];
    const float* w2 = (const float*)d_in[5];
    const float* b2 = (const float*)d_in[6];
    const float* dw = (const float*)d_in[7];
    const float* db = (const float*)d_in[8];
    float* out = (float*)d_out;

    // ws layout (float units):
    // feat [2*256*2304] | off [2*18*2304] | wTl bf16 [256*2304] | w1b bf16 [256*4608]
    float* feat = (float*)d_ws;
    float* off  = feat + 2 * 256 * 2304;                            // 1,179,648
    unsigned short* wTl = (unsigned short*)(off + 2 * 18 * 2304);   // 589,824 bf16
    unsigned short* w1b = wTl + 256 * 2304;                         // 1,179,648 bf16

    hipLaunchKernelGGL(k_cast,   dim3(2304),      dim3(256), 0, stream, dw, wTl);
    hipLaunchKernelGGL(k_cast,   dim3(4608),      dim3(256), 0, stream, w1, w1b);
    hipLaunchKernelGGL(k_binit,  dim3(4608),      dim3(256), 0, stream, b1, feat);
    hipLaunchKernelGGL(k_conv1,  dim3(72, 2, 2),  dim3(256), 0, stream, q, k, w1b, feat);
    hipLaunchKernelGGL(k_conv2,  dim3(9, 18, 2),  dim3(256), 0, stream, feat, w2, b2, off);
    hipLaunchKernelGGL(k_deform, dim3(72, 8),     dim3(256), 0, stream, v, off, wTl, db, q, out);
}

// Round 4
// 470.529 us; speedup vs baseline: 2.2249x; 1.1154x over previous
//
#include <hip/hip_runtime.h>

// Problem constants: B=2, obj=4, C=256, H=W=48, N=8, HW=2304
#define HH 48
#define WW 48
#define HWP 2304
#define CC 256
#define NB 8
#define QKROW 2305   // 2304 rows + 1 zero pad row (index 2304) for OOB taps

typedef __attribute__((ext_vector_type(8))) short short8;   // 8 x bf16 = 4 VGPR
typedef __attribute__((ext_vector_type(4))) float floatx4;  // MFMA C/D frag

static __device__ __forceinline__ unsigned short f2bf(float f) {
    union { float f; unsigned u; } v; v.f = f;
    unsigned r = v.u + 0x7fffu + ((v.u >> 16) & 1u);        // RNE
    return (unsigned short)(r >> 16);
}
static __device__ __forceinline__ float bf2f(short v) {
    union { unsigned u; float f; } x; x.u = ((unsigned)(unsigned short)v) << 16;
    return x.f;
}

// ---- qkT[b][row][c2]: channels-last bf16 concat(q,k); row 2304 = zeros -----
__global__ __launch_bounds__(256) void k_qkT(const float* __restrict__ q,
        const float* __restrict__ kk, unsigned short* __restrict__ qkT) {
    int row = blockIdx.x;                 // 0..2304
    int b   = blockIdx.y;
    int c   = threadIdx.x;                // 0..255
    unsigned short* dst = qkT + ((size_t)b * QKROW + row) * 512;
    if (row < HWP) {
        dst[c]       = f2bf(q [((size_t)b * CC + c) * HWP + row]);
        dst[c + 256] = f2bf(kk[((size_t)b * CC + c) * HWP + row]);
    } else {
        dst[c] = 0; dst[c + 256] = 0;
    }
}

// ---- vT[n][p][c]: channels-last bf16 value ---------------------------------
__global__ __launch_bounds__(256) void k_vT(const float* __restrict__ v,
                                            unsigned short* __restrict__ vT) {
    int row = blockIdx.x;                 // p
    int n   = blockIdx.y;
    int c   = threadIdx.x;
    vT[((size_t)n * HWP + row) * 256 + c] = f2bf(v[((size_t)n * CC + c) * HWP + row]);
}

// ---- w1r[o][tap*512+c2] = bf16(w1[o][c2][tap]) -----------------------------
__global__ __launch_bounds__(256) void k_w1r(const float* __restrict__ w1,
                                             unsigned short* __restrict__ w1r) {
    int idx = blockIdx.x * 256 + threadIdx.x;   // 256*4608
    int o = idx / 4608, r = idx % 4608, tap = r / 512, c = r & 511;
    w1r[idx] = f2bf(w1[((size_t)o * 512 + c) * 9 + tap]);
}

// ---- wdr[o][tap*256+c] = bf16(dw[o][c][tap]) -------------------------------
__global__ __launch_bounds__(256) void k_wdr(const float* __restrict__ dw,
                                             unsigned short* __restrict__ wdr) {
    int idx = blockIdx.x * 256 + threadIdx.x;   // 256*2304
    int o = idx / 2304, r = idx % 2304, tap = r / 256, c = r & 255;
    wdr[idx] = f2bf(dw[((size_t)o * 256 + c) * 9 + tap]);
}

// ---- w2r[o2][tap*256+c], o2<32, rows 18..31 zero ---------------------------
__global__ __launch_bounds__(256) void k_w2r(const float* __restrict__ w2,
                                             unsigned short* __restrict__ w2r) {
    int idx = blockIdx.x * 256 + threadIdx.x;   // 32*2304
    int o = idx / 2304, r = idx % 2304, tap = r / 256, c = r & 255;
    w2r[idx] = (o < 18) ? f2bf(w2[((size_t)o * 256 + c) * 9 + tap]) : 0;
}

// ---- zero featb pad rows ----------------------------------------------------
__global__ __launch_bounds__(256) void k_zrow(unsigned short* __restrict__ featb) {
    int c = threadIdx.x;
    featb[((size_t)(0 * QKROW) + HWP) * 256 + c] = 0;
    featb[((size_t)(1 * QKROW) + HWP) * 256 + c] = 0;
}

// ---- conv1 as pure-MFMA GEMM, no LDS ---------------------------------------
// M=256 (o), 16 p per wave, K=4608 tap-major. B-frag = shifted row load from
// qkT (OOB taps -> zero pad row). Out: featb[b][p][o] bf16 with fused bias.
__global__ __launch_bounds__(256) void k_conv1(const unsigned short* __restrict__ qkT,
        const unsigned short* __restrict__ w1r, const float* __restrict__ b1,
        unsigned short* __restrict__ featb) {
    const int tid = threadIdx.x;
    const int pb  = blockIdx.x;           // 144
    const int b   = blockIdx.y;
    const int lane = tid & 63, wv = tid >> 6;
    const int lo = lane & 15, quad = lane >> 4;
    const int pp = pb * 16 + lo;
    const int h = pp / WW, w = pp - (pp / WW) * WW;

    int broff[9];
#pragma unroll
    for (int t = 0; t < 9; t++) {
        int dy = t / 3 - 1, dx = t % 3 - 1;
        bool val = (h + dy >= 0) && (h + dy < HH) && (w + dx >= 0) && (w + dx < WW);
        int row = val ? (pp + dy * WW + dx) : HWP;
        broff[t] = (b * QKROW + row) * 512;
    }

    floatx4 acc[4];
#pragma unroll
    for (int mt = 0; mt < 4; mt++) acc[mt] = (floatx4)0.f;

    const unsigned short* aBase = w1r + (size_t)(wv * 64 + lo) * 4608 + quad * 8;

    for (int tap = 0; tap < 9; tap++) {
        const unsigned short* brow = qkT + broff[tap] + quad * 8;
        const unsigned short* arow = aBase + tap * 512;
#pragma unroll 4
        for (int ks = 0; ks < 16; ks++) {
            short8 bf = *(const short8*)(brow + ks * 32);
            short8 a0 = *(const short8*)(arow + ks * 32);
            short8 a1 = *(const short8*)(arow + ks * 32 + 16 * 4608);
            short8 a2 = *(const short8*)(arow + ks * 32 + 32 * 4608);
            short8 a3 = *(const short8*)(arow + ks * 32 + 48 * 4608);
            acc[0] = __builtin_amdgcn_mfma_f32_16x16x32_bf16(a0, bf, acc[0], 0, 0, 0);
            acc[1] = __builtin_amdgcn_mfma_f32_16x16x32_bf16(a1, bf, acc[1], 0, 0, 0);
            acc[2] = __builtin_amdgcn_mfma_f32_16x16x32_bf16(a2, bf, acc[2], 0, 0, 0);
            acc[3] = __builtin_amdgcn_mfma_f32_16x16x32_bf16(a3, bf, acc[3], 0, 0, 0);
        }
    }

    // C/D: col(p)=lane&15, row(o)=quad*4+reg
#pragma unroll
    for (int mt = 0; mt < 4; mt++) {
        int o = wv * 64 + mt * 16 + quad * 4;
        unsigned r01 = (unsigned)f2bf(acc[mt][0] + b1[o])
                     | ((unsigned)f2bf(acc[mt][1] + b1[o + 1]) << 16);
        unsigned r23 = (unsigned)f2bf(acc[mt][2] + b1[o + 2])
                     | ((unsigned)f2bf(acc[mt][3] + b1[o + 3]) << 16);
        uint2 pk; pk.x = r01; pk.y = r23;
        *(uint2*)(featb + ((size_t)(b * QKROW) + pp) * 256 + o) = pk;
    }
}

// ---- conv2: M=32 (18 live), same structure, reads featb --------------------
__global__ __launch_bounds__(256) void k_conv2(const unsigned short* __restrict__ featb,
        const unsigned short* __restrict__ w2r, const float* __restrict__ b2,
        float* __restrict__ off) {
    const int tid = threadIdx.x;
    const int pb = blockIdx.x;            // 36
    const int b  = blockIdx.y;
    const int lane = tid & 63, wv = tid >> 6;
    const int lo = lane & 15, quad = lane >> 4;
    const int pp = pb * 64 + wv * 16 + lo;
    const int h = pp / WW, w = pp - (pp / WW) * WW;

    int broff[9];
#pragma unroll
    for (int t = 0; t < 9; t++) {
        int dy = t / 3 - 1, dx = t % 3 - 1;
        bool val = (h + dy >= 0) && (h + dy < HH) && (w + dx >= 0) && (w + dx < WW);
        int row = val ? (pp + dy * WW + dx) : HWP;
        broff[t] = (b * QKROW + row) * 256;
    }

    floatx4 acc[2];
    acc[0] = (floatx4)0.f; acc[1] = (floatx4)0.f;
    const unsigned short* aBase = w2r + (size_t)lo * 2304 + quad * 8;

    for (int tap = 0; tap < 9; tap++) {
        const unsigned short* brow = featb + broff[tap] + quad * 8;
        const unsigned short* arow = aBase + tap * 256;
#pragma unroll
        for (int ks = 0; ks < 8; ks++) {
            short8 bf = *(const short8*)(brow + ks * 32);
            short8 a0 = *(const short8*)(arow + ks * 32);
            short8 a1 = *(const short8*)(arow + ks * 32 + 16 * 2304);
            acc[0] = __builtin_amdgcn_mfma_f32_16x16x32_bf16(a0, bf, acc[0], 0, 0, 0);
            acc[1] = __builtin_amdgcn_mfma_f32_16x16x32_bf16(a1, bf, acc[1], 0, 0, 0);
        }
    }

#pragma unroll
    for (int mt = 0; mt < 2; mt++)
#pragma unroll
        for (int j = 0; j < 4; j++) {
            int o = mt * 16 + quad * 4 + j;
            if (o < 18) off[((size_t)b * 18 + o) * HWP + pp] = acc[mt][j] + b2[o];
        }
}

// ---- deform: per-tap LDS chunks from vT, MFMA GEMM, fused epilogue ---------
// Block = (n, 64 p). 4 waves: wave wv = o-block (64 o), each 64o x 64p.
// Chunk = one tap: stage Sl[64 p][256 c] bf16 (XOR-swizzled 16B granules).
__global__ __launch_bounds__(256) void k_deform(const unsigned short* __restrict__ vT,
        const float* __restrict__ off, const unsigned short* __restrict__ wdr,
        const float* __restrict__ db, const float* __restrict__ q,
        float* __restrict__ out) {
    __shared__ __align__(16) unsigned short Sl[64 * 256];   // 32 KB

    const int tid = threadIdx.x;
    const int pb  = blockIdx.x;           // 36
    const int n   = blockIdx.y;           // 8
    const int b   = n >> 2;
    const int ps  = tid & 63;             // staging: pixel per lane
    const int cq  = tid >> 6;             // staging: c-quarter
    const int pp  = pb * 64 + ps;
    const int h   = pp / WW, w = pp - (pp / WW) * WW;

    const int lane = tid & 63, wv = tid >> 6;
    const int lo = lane & 15, quad = lane >> 4;

    floatx4 acc[4][4];                    // [mt][nt]
#pragma unroll
    for (int mt = 0; mt < 4; mt++)
#pragma unroll
        for (int nt = 0; nt < 4; nt++) acc[mt][nt] = (floatx4)0.f;

    const unsigned short* vTn   = vT + (size_t)n * HWP * 256;
    const unsigned short* aBase = wdr + (size_t)(wv * 64 + lo) * 2304 + quad * 8;

    for (int tap = 0; tap < 9; tap++) {
        // bilinear corners for (pp, tap)
        float dy = off[((size_t)b * 18 + 2 * tap) * HWP + pp];
        float dx = off[((size_t)b * 18 + 2 * tap + 1) * HWP + pp];
        float py = dy + (float)h + (float)(tap / 3 - 1);
        float px = dx + (float)w + (float)(tap % 3 - 1);
        float y0f = floorf(py), x0f = floorf(px);
        int y0 = (int)y0f, x0 = (int)x0f;
        float fy = py - y0f, fx = px - x0f;
        bool y0ok = (y0 >= 0) & (y0 < HH), y1ok = (y0 >= -1) & (y0 < HH - 1);
        bool x0ok = (x0 >= 0) & (x0 < WW), x1ok = (x0 >= -1) & (x0 < WW - 1);
        int y0c = min(max(y0, 0), HH - 1), y1c = min(max(y0 + 1, 0), HH - 1);
        int x0c = min(max(x0, 0), WW - 1), x1c = min(max(x0 + 1, 0), WW - 1);
        int   i0 = y0c * WW + x0c, i1 = y0c * WW + x1c;
        int   i2 = y1c * WW + x0c, i3 = y1c * WW + x1c;
        float w0 = (y0ok && x0ok) ? (1.f - fy) * (1.f - fx) : 0.f;
        float w1 = (y0ok && x1ok) ? (1.f - fy) * fx         : 0.f;
        float w2 = (y1ok && x0ok) ? fy * (1.f - fx)         : 0.f;
        float w3 = (y1ok && x1ok) ? fy * fx                 : 0.f;

        const unsigned short* r0 = vTn + (size_t)i0 * 256;
        const unsigned short* r1 = vTn + (size_t)i1 * 256;
        const unsigned short* r2 = vTn + (size_t)i2 * 256;
        const unsigned short* r3 = vTn + (size_t)i3 * 256;
#pragma unroll
        for (int cg = 0; cg < 8; cg++) {
            int c = cq * 64 + cg * 8;
            short8 a0 = *(const short8*)(r0 + c);
            short8 a1 = *(const short8*)(r1 + c);
            short8 a2 = *(const short8*)(r2 + c);
            short8 a3 = *(const short8*)(r3 + c);
            short8 ov;
#pragma unroll
            for (int j = 0; j < 8; j++) {
                float s = w0 * bf2f(a0[j]) + w1 * bf2f(a1[j])
                        + w2 * bf2f(a2[j]) + w3 * bf2f(a3[j]);
                ov[j] = (short)f2bf(s);
            }
            int gr = (c >> 3) ^ (ps & 7);           // XOR-swizzle 16B granules
            *(short8*)(Sl + ps * 256 + gr * 8) = ov;
        }
        __syncthreads();

        const unsigned short* arow = aBase + tap * 256;
#pragma unroll
        for (int ks = 0; ks < 8; ks++) {
            short8 a0 = *(const short8*)(arow + ks * 32);
            short8 a1 = *(const short8*)(arow + ks * 32 + 16 * 2304);
            short8 a2 = *(const short8*)(arow + ks * 32 + 32 * 2304);
            short8 a3 = *(const short8*)(arow + ks * 32 + 48 * 2304);
            short8 bf[4];
#pragma unroll
            for (int nt = 0; nt < 4; nt++) {
                int row = nt * 16 + lo;
                int gr = (ks * 4 + quad) ^ (lo & 7);
                bf[nt] = *(const short8*)(Sl + row * 256 + gr * 8);
            }
#pragma unroll
            for (int nt = 0; nt < 4; nt++) {
                acc[0][nt] = __builtin_amdgcn_mfma_f32_16x16x32_bf16(a0, bf[nt], acc[0][nt], 0, 0, 0);
                acc[1][nt] = __builtin_amdgcn_mfma_f32_16x16x32_bf16(a1, bf[nt], acc[1][nt], 0, 0, 0);
                acc[2][nt] = __builtin_amdgcn_mfma_f32_16x16x32_bf16(a2, bf[nt], acc[2][nt], 0, 0, 0);
                acc[3][nt] = __builtin_amdgcn_mfma_f32_16x16x32_bf16(a3, bf[nt], acc[3][nt], 0, 0, 0);
            }
        }
        __syncthreads();
    }

    // epilogue: out[p][n][o] = acc + db[o] + q[b][o][p]
#pragma unroll
    for (int mt = 0; mt < 4; mt++) {
        int o = wv * 64 + mt * 16 + quad * 4;
        float d0 = db[o], d1 = db[o + 1], d2 = db[o + 2], d3 = db[o + 3];
#pragma unroll
        for (int nt = 0; nt < 4; nt++) {
            int pq = pb * 64 + nt * 16 + lo;
            floatx4 r = acc[mt][nt];
            r[0] += d0 + q[((size_t)b * CC + o + 0) * HWP + pq];
            r[1] += d1 + q[((size_t)b * CC + o + 1) * HWP + pq];
            r[2] += d2 + q[((size_t)b * CC + o + 2) * HWP + pq];
            r[3] += d3 + q[((size_t)b * CC + o + 3) * HWP + pq];
            *(floatx4*)(out + ((size_t)pq * NB + n) * CC + o) = r;
        }
    }
}

extern "C" void kernel_launch(void* const* d_in, const int* in_sizes, int n_in,
                              void* d_out, int out_size, void* d_ws, size_t ws_size,
                              hipStream_t stream) {
    const float* q  = (const float*)d_in[0];
    const float* k  = (const float*)d_in[1];
    const float* v  = (const float*)d_in[2];
    const float* w1 = (const float*)d_in[3];
    const float* b1 = (const float*)d_in[4];
    const float* w2 = (const float*)d_in[5];
    const float* b2 = (const float*)d_in[6];
    const float* dw = (const float*)d_in[7];
    const float* db = (const float*)d_in[8];
    float* out = (float*)d_out;

    // ws layout: off fp32 | qkT | vT | featb | w1r | wdr | w2r (bf16)  ~20.5 MB
    float* off = (float*)d_ws;
    unsigned short* qkT   = (unsigned short*)(off + 82944);
    unsigned short* vT    = qkT + 2360320;      // 2*2305*512
    unsigned short* featb = vT + 4718592;       // 8*2304*256
    unsigned short* w1r   = featb + 1180160;    // 2*2305*256
    unsigned short* wdr   = w1r + 1179648;      // 256*4608
    unsigned short* w2r   = wdr + 589824;       // 256*2304

    hipLaunchKernelGGL(k_qkT,    dim3(2305, 2), dim3(256), 0, stream, q, k, qkT);
    hipLaunchKernelGGL(k_vT,     dim3(2304, 8), dim3(256), 0, stream, v, vT);
    hipLaunchKernelGGL(k_w1r,    dim3(4608),    dim3(256), 0, stream, w1, w1r);
    hipLaunchKernelGGL(k_wdr,    dim3(2304),    dim3(256), 0, stream, dw, wdr);
    hipLaunchKernelGGL(k_w2r,    dim3(288),     dim3(256), 0, stream, w2, w2r);
    hipLaunchKernelGGL(k_zrow,   dim3(1),       dim3(256), 0, stream, featb);
    hipLaunchKernelGGL(k_conv1,  dim3(144, 2),  dim3(256), 0, stream, qkT, w1r, b1, featb);
    hipLaunchKernelGGL(k_conv2,  dim3(36, 2),   dim3(256), 0, stream, featb, w2r, b2, off);
    hipLaunchKernelGGL(k_deform, dim3(36, 8),   dim3(256), 0, stream, vT, off, wdr, db, q, out);
}

// Round 5
// 393.797 us; speedup vs baseline: 2.6585x; 1.1949x over previous
//
#include <hip/hip_runtime.h>

// Problem constants: B=2, obj=4, C=256, H=W=48, N=8, HW=2304
#define HH 48
#define WW 48
#define HWP 2304
#define CC 256
#define NB 8
#define QKROW 2305   // 2304 rows + 1 zero pad row (index 2304) for OOB taps

typedef __attribute__((ext_vector_type(8))) short short8;   // 8 x bf16 = 4 VGPR
typedef __attribute__((ext_vector_type(4))) float floatx4;  // MFMA C/D frag

static __device__ __forceinline__ unsigned short f2bf(float f) {
    union { float f; unsigned u; } v; v.f = f;
    unsigned r = v.u + 0x7fffu + ((v.u >> 16) & 1u);        // RNE
    return (unsigned short)(r >> 16);
}
static __device__ __forceinline__ float bf2f(short v) {
    union { unsigned u; float f; } x; x.u = ((unsigned)(unsigned short)v) << 16;
    return x.f;
}

// ---- tiled transpose q/k -> qkT[b][px][c2] bf16 (64x64 tiles via LDS) ------
__global__ __launch_bounds__(256) void k_tr_qk(const float* __restrict__ q,
        const float* __restrict__ kk, unsigned short* __restrict__ qkT) {
    __shared__ float T[64][65];
    const int pg = blockIdx.x, cg = blockIdx.y;
    const int b = blockIdx.z >> 1, src = blockIdx.z & 1;
    const float* s = (src ? kk : q) + (size_t)b * CC * HWP;
    const int tx = threadIdx.x & 63, ty = threadIdx.x >> 6;
#pragma unroll
    for (int i = 0; i < 16; i++) {
        int cl = ty * 16 + i;
        T[cl][tx] = s[(size_t)(cg * 64 + cl) * HWP + pg * 64 + tx];
    }
    __syncthreads();
#pragma unroll
    for (int i = 0; i < 16; i++) {
        int pxl = ty * 16 + i;
        qkT[((size_t)b * QKROW + pg * 64 + pxl) * 512 + src * 256 + cg * 64 + tx]
            = f2bf(T[tx][pxl]);
    }
}

// ---- tiled transpose value -> vT[n][px][c] bf16 ----------------------------
__global__ __launch_bounds__(256) void k_tr_v(const float* __restrict__ v,
                                              unsigned short* __restrict__ vT) {
    __shared__ float T[64][65];
    const int pg = blockIdx.x, cg = blockIdx.y, n = blockIdx.z;
    const float* s = v + (size_t)n * CC * HWP;
    const int tx = threadIdx.x & 63, ty = threadIdx.x >> 6;
#pragma unroll
    for (int i = 0; i < 16; i++) {
        int cl = ty * 16 + i;
        T[cl][tx] = s[(size_t)(cg * 64 + cl) * HWP + pg * 64 + tx];
    }
    __syncthreads();
#pragma unroll
    for (int i = 0; i < 16; i++) {
        int pxl = ty * 16 + i;
        vT[((size_t)n * HWP + pg * 64 + pxl) * 256 + cg * 64 + tx] = f2bf(T[tx][pxl]);
    }
}

// ---- weight reorders (tap-major, bf16) -------------------------------------
__global__ __launch_bounds__(256) void k_w1r(const float* __restrict__ w1,
                                             unsigned short* __restrict__ w1r) {
    int idx = blockIdx.x * 256 + threadIdx.x;   // 256*4608
    int o = idx / 4608, r = idx % 4608, tap = r / 512, c = r & 511;
    w1r[idx] = f2bf(w1[((size_t)o * 512 + c) * 9 + tap]);
}
__global__ __launch_bounds__(256) void k_wdr(const float* __restrict__ dw,
                                             unsigned short* __restrict__ wdr) {
    int idx = blockIdx.x * 256 + threadIdx.x;   // 256*2304
    int o = idx / 2304, r = idx % 2304, tap = r / 256, c = r & 255;
    wdr[idx] = f2bf(dw[((size_t)o * 256 + c) * 9 + tap]);
}
__global__ __launch_bounds__(256) void k_w2r(const float* __restrict__ w2,
                                             unsigned short* __restrict__ w2r) {
    int idx = blockIdx.x * 256 + threadIdx.x;   // 32*2304
    int o = idx / 2304, r = idx % 2304, tap = r / 256, c = r & 255;
    w2r[idx] = (o < 18) ? f2bf(w2[((size_t)o * 256 + c) * 9 + tap]) : 0;
}

// ---- zero qkT pad rows ------------------------------------------------------
__global__ __launch_bounds__(256) void k_pads(unsigned short* __restrict__ qkT) {
    int t = threadIdx.x;
#pragma unroll
    for (int b = 0; b < 2; b++) {
        qkT[((size_t)b * QKROW + HWP) * 512 + t] = 0;
        qkT[((size_t)b * QKROW + HWP) * 512 + 256 + t] = 0;
    }
}

// ---- conv1: tap-split(3) MFMA GEMM -> fp32 partials feat3[g][b][px][o] -----
// grid (144 px-tiles, 2 b, 3 tap-groups). 4 waves x (64o x 16px), K=1536.
__global__ __launch_bounds__(256) void k_conv1(const unsigned short* __restrict__ qkT,
        const unsigned short* __restrict__ w1r, float* __restrict__ feat3) {
    const int tid = threadIdx.x;
    const int pb = blockIdx.x;            // 144
    const int b  = blockIdx.y;
    const int g  = blockIdx.z;            // tap row (dy = g-1)
    const int lane = tid & 63, wv = tid >> 6;
    const int lo = lane & 15, quad = lane >> 4;
    const int pp = pb * 16 + lo;
    const int h = pp / WW, w = pp - (pp / WW) * WW;

    floatx4 acc[4];
#pragma unroll
    for (int mt = 0; mt < 4; mt++) acc[mt] = (floatx4)0.f;

    const unsigned short* aBase = w1r + (size_t)(wv * 64 + lo) * 4608 + quad * 8;

#pragma unroll
    for (int t3 = 0; t3 < 3; t3++) {
        const int tap = g * 3 + t3;
        const int dy = g - 1, dx = t3 - 1;
        const bool val = (h + dy >= 0) && (h + dy < HH) && (w + dx >= 0) && (w + dx < WW);
        const int row = val ? (pp + dy * WW + dx) : HWP;
        const unsigned short* brow = qkT + ((size_t)b * QKROW + row) * 512 + quad * 8;
        const unsigned short* arow = aBase + tap * 512;
#pragma unroll 4
        for (int ks = 0; ks < 16; ks++) {
            short8 bf = *(const short8*)(brow + ks * 32);
            short8 a0 = *(const short8*)(arow + ks * 32);
            short8 a1 = *(const short8*)(arow + ks * 32 + 16 * 4608);
            short8 a2 = *(const short8*)(arow + ks * 32 + 32 * 4608);
            short8 a3 = *(const short8*)(arow + ks * 32 + 48 * 4608);
            acc[0] = __builtin_amdgcn_mfma_f32_16x16x32_bf16(a0, bf, acc[0], 0, 0, 0);
            acc[1] = __builtin_amdgcn_mfma_f32_16x16x32_bf16(a1, bf, acc[1], 0, 0, 0);
            acc[2] = __builtin_amdgcn_mfma_f32_16x16x32_bf16(a2, bf, acc[2], 0, 0, 0);
            acc[3] = __builtin_amdgcn_mfma_f32_16x16x32_bf16(a3, bf, acc[3], 0, 0, 0);
        }
    }

    float* dst = feat3 + (((size_t)g * 2 + b) * HWP + pp) * 256;
#pragma unroll
    for (int mt = 0; mt < 4; mt++) {
        int o = wv * 64 + mt * 16 + quad * 4;
        *(floatx4*)(dst + o) = acc[mt];
    }
}

// ---- fcast: featb[b][px][o] = bf16(sum_g feat3 + b1), pad row zero ---------
__global__ __launch_bounds__(256) void k_fcast(const float* __restrict__ feat3,
        const float* __restrict__ b1, unsigned short* __restrict__ featb) {
    const int row = blockIdx.x;           // 0..2304
    const int b = blockIdx.y;
    const int c = threadIdx.x;
    size_t oidx = ((size_t)b * QKROW + row) * 256 + c;
    if (row < HWP) {
        float s = feat3[(((size_t)0 * 2 + b) * HWP + row) * 256 + c]
                + feat3[(((size_t)1 * 2 + b) * HWP + row) * 256 + c]
                + feat3[(((size_t)2 * 2 + b) * HWP + row) * 256 + c] + b1[c];
        featb[oidx] = f2bf(s);
    } else {
        featb[oidx] = 0;
    }
}

// ---- conv2: tap-split(9) -> fp32 partials off9[t][b][px][32] ---------------
// grid (36 px-tiles, 2 b, 9 taps). 4 waves x (32o x 16px), K=256.
__global__ __launch_bounds__(256) void k_conv2(const unsigned short* __restrict__ featb,
        const unsigned short* __restrict__ w2r, float* __restrict__ off9) {
    const int tid = threadIdx.x;
    const int pb = blockIdx.x;            // 36
    const int b  = blockIdx.y;
    const int tap = blockIdx.z;
    const int lane = tid & 63, wv = tid >> 6;
    const int lo = lane & 15, quad = lane >> 4;
    const int pp = pb * 64 + wv * 16 + lo;
    const int h = pp / WW, w = pp - (pp / WW) * WW;
    const int dy = tap / 3 - 1, dx = tap % 3 - 1;
    const bool val = (h + dy >= 0) && (h + dy < HH) && (w + dx >= 0) && (w + dx < WW);
    const int row = val ? (pp + dy * WW + dx) : HWP;

    const unsigned short* brow = featb + ((size_t)b * QKROW + row) * 256 + quad * 8;
    const unsigned short* arow = w2r + (size_t)lo * 2304 + tap * 256 + quad * 8;

    floatx4 acc[2];
    acc[0] = (floatx4)0.f; acc[1] = (floatx4)0.f;
#pragma unroll
    for (int ks = 0; ks < 8; ks++) {
        short8 bf = *(const short8*)(brow + ks * 32);
        short8 a0 = *(const short8*)(arow + ks * 32);
        short8 a1 = *(const short8*)(arow + ks * 32 + 16 * 2304);
        acc[0] = __builtin_amdgcn_mfma_f32_16x16x32_bf16(a0, bf, acc[0], 0, 0, 0);
        acc[1] = __builtin_amdgcn_mfma_f32_16x16x32_bf16(a1, bf, acc[1], 0, 0, 0);
    }

    float* dst = off9 + (((size_t)tap * 2 + b) * HWP + pp) * 32;
#pragma unroll
    for (int mt = 0; mt < 2; mt++) {
        int o = mt * 16 + quad * 4;
        *(floatx4*)(dst + o) = acc[mt];
    }
}

// ---- osum: off[b][o][px] = sum_t off9 + b2[o]  (o<18) ----------------------
__global__ __launch_bounds__(256) void k_osum(const float* __restrict__ off9,
        const float* __restrict__ b2, float* __restrict__ off) {
    int i = blockIdx.x * 256 + threadIdx.x;        // < 2*18*2304
    int b = i / (18 * HWP);
    int r = i - b * 18 * HWP;
    int o = r / HWP, px = r - o * HWP;
    float s = b2[o];
#pragma unroll
    for (int t = 0; t < 9; t++)
        s += off9[(((size_t)t * 2 + b) * HWP + px) * 32 + o];
    off[i] = s;
}

// ---- deform: 32px tiles, per-tap LDS staging, MFMA, fused epilogue ---------
// grid (72 px-tiles, 8 n). 4 waves x (64o x 32px). LDS 16 KB.
__global__ __launch_bounds__(256) void k_deform(const unsigned short* __restrict__ vT,
        const float* __restrict__ off, const unsigned short* __restrict__ wdr,
        const float* __restrict__ db, const float* __restrict__ q,
        float* __restrict__ out) {
    __shared__ __align__(16) unsigned short Sl[32 * 256];   // 16 KB

    const int tid = threadIdx.x;
    const int pb  = blockIdx.x;           // 72
    const int n   = blockIdx.y;           // 8
    const int b   = n >> 2;
    const int ps  = tid & 31;             // staging pixel
    const int cq  = tid >> 5;             // staging c-eighth (32 c each)
    const int pp  = pb * 32 + ps;
    const int h   = pp / WW, w = pp - (pp / WW) * WW;

    const int lane = tid & 63, wv = tid >> 6;
    const int lo = lane & 15, quad = lane >> 4;

    floatx4 acc[4][2];
#pragma unroll
    for (int mt = 0; mt < 4; mt++)
#pragma unroll
        for (int nt = 0; nt < 2; nt++) acc[mt][nt] = (floatx4)0.f;

    const unsigned short* vTn   = vT + (size_t)n * HWP * 256;
    const unsigned short* aBase = wdr + (size_t)(wv * 64 + lo) * 2304 + quad * 8;

    for (int tap = 0; tap < 9; tap++) {
        float dy = off[((size_t)b * 18 + 2 * tap) * HWP + pp];
        float dx = off[((size_t)b * 18 + 2 * tap + 1) * HWP + pp];
        float py = dy + (float)h + (float)(tap / 3 - 1);
        float px = dx + (float)w + (float)(tap % 3 - 1);
        float y0f = floorf(py), x0f = floorf(px);
        int y0 = (int)y0f, x0 = (int)x0f;
        float fy = py - y0f, fx = px - x0f;
        bool y0ok = (y0 >= 0) & (y0 < HH), y1ok = (y0 >= -1) & (y0 < HH - 1);
        bool x0ok = (x0 >= 0) & (x0 < WW), x1ok = (x0 >= -1) & (x0 < WW - 1);
        int y0c = min(max(y0, 0), HH - 1), y1c = min(max(y0 + 1, 0), HH - 1);
        int x0c = min(max(x0, 0), WW - 1), x1c = min(max(x0 + 1, 0), WW - 1);
        int   i0 = y0c * WW + x0c, i1 = y0c * WW + x1c;
        int   i2 = y1c * WW + x0c, i3 = y1c * WW + x1c;
        float w0 = (y0ok && x0ok) ? (1.f - fy) * (1.f - fx) : 0.f;
        float w1 = (y0ok && x1ok) ? (1.f - fy) * fx         : 0.f;
        float w2 = (y1ok && x0ok) ? fy * (1.f - fx)         : 0.f;
        float w3 = (y1ok && x1ok) ? fy * fx                 : 0.f;

        const unsigned short* r0 = vTn + (size_t)i0 * 256;
        const unsigned short* r1 = vTn + (size_t)i1 * 256;
        const unsigned short* r2 = vTn + (size_t)i2 * 256;
        const unsigned short* r3 = vTn + (size_t)i3 * 256;
#pragma unroll
        for (int cg = 0; cg < 4; cg++) {
            int c = cq * 32 + cg * 8;
            short8 a0 = *(const short8*)(r0 + c);
            short8 a1 = *(const short8*)(r1 + c);
            short8 a2 = *(const short8*)(r2 + c);
            short8 a3 = *(const short8*)(r3 + c);
            short8 ov;
#pragma unroll
            for (int j = 0; j < 8; j++) {
                float s = w0 * bf2f(a0[j]) + w1 * bf2f(a1[j])
                        + w2 * bf2f(a2[j]) + w3 * bf2f(a3[j]);
                ov[j] = (short)f2bf(s);
            }
            int gr = (c >> 3) ^ (ps & 7);           // XOR-swizzled 16B granules
            *(short8*)(Sl + ps * 256 + gr * 8) = ov;
        }
        __syncthreads();

        const unsigned short* arow = aBase + tap * 256;
#pragma unroll
        for (int ks = 0; ks < 8; ks++) {
            short8 a0 = *(const short8*)(arow + ks * 32);
            short8 a1 = *(const short8*)(arow + ks * 32 + 16 * 2304);
            short8 a2 = *(const short8*)(arow + ks * 32 + 32 * 2304);
            short8 a3 = *(const short8*)(arow + ks * 32 + 48 * 2304);
            short8 bf[2];
#pragma unroll
            for (int nt = 0; nt < 2; nt++) {
                int row = nt * 16 + lo;
                int gr = (ks * 4 + quad) ^ (lo & 7);
                bf[nt] = *(const short8*)(Sl + row * 256 + gr * 8);
            }
#pragma unroll
            for (int nt = 0; nt < 2; nt++) {
                acc[0][nt] = __builtin_amdgcn_mfma_f32_16x16x32_bf16(a0, bf[nt], acc[0][nt], 0, 0, 0);
                acc[1][nt] = __builtin_amdgcn_mfma_f32_16x16x32_bf16(a1, bf[nt], acc[1][nt], 0, 0, 0);
                acc[2][nt] = __builtin_amdgcn_mfma_f32_16x16x32_bf16(a2, bf[nt], acc[2][nt], 0, 0, 0);
                acc[3][nt] = __builtin_amdgcn_mfma_f32_16x16x32_bf16(a3, bf[nt], acc[3][nt], 0, 0, 0);
            }
        }
        __syncthreads();
    }

    // epilogue: out[p][n][o] = acc + db[o] + q[b][o][p]
#pragma unroll
    for (int mt = 0; mt < 4; mt++) {
        int o = wv * 64 + mt * 16 + quad * 4;
        float d0 = db[o], d1 = db[o + 1], d2 = db[o + 2], d3 = db[o + 3];
#pragma unroll
        for (int nt = 0; nt < 2; nt++) {
            int pq = pb * 32 + nt * 16 + lo;
            floatx4 r = acc[mt][nt];
            r[0] += d0 + q[((size_t)b * CC + o + 0) * HWP + pq];
            r[1] += d1 + q[((size_t)b * CC + o + 1) * HWP + pq];
            r[2] += d2 + q[((size_t)b * CC + o + 2) * HWP + pq];
            r[3] += d3 + q[((size_t)b * CC + o + 3) * HWP + pq];
            *(floatx4*)(out + ((size_t)pq * NB + n) * CC + o) = r;
        }
    }
}

extern "C" void kernel_launch(void* const* d_in, const int* in_sizes, int n_in,
                              void* d_out, int out_size, void* d_ws, size_t ws_size,
                              hipStream_t stream) {
    const float* q  = (const float*)d_in[0];
    const float* k  = (const float*)d_in[1];
    const float* v  = (const float*)d_in[2];
    const float* w1 = (const float*)d_in[3];
    const float* b1 = (const float*)d_in[4];
    const float* w2 = (const float*)d_in[5];
    const float* b2 = (const float*)d_in[6];
    const float* dw = (const float*)d_in[7];
    const float* db = (const float*)d_in[8];
    float* out = (float*)d_out;

    // ws layout (~40 MB): off | feat3 | off9 (fp32) || qkT | vT | featb | w1r | wdr | w2r (bf16)
    float* off   = (float*)d_ws;                          //   82,944 f
    float* feat3 = off + 82944;                           // 3,538,944 f
    float* off9  = feat3 + 3538944;                       // 1,327,104 f
    unsigned short* qkT   = (unsigned short*)(off9 + 1327104);
    unsigned short* vT    = qkT + 2360320;                // 2*2305*512
    unsigned short* featb = vT + 4718592;                 // 8*2304*256
    unsigned short* w1r   = featb + 1180160;              // 2*2305*256
    unsigned short* wdr   = w1r + 1179648;                // 256*4608
    unsigned short* w2r   = wdr + 589824;                 // 256*2304 (+73728)

    hipLaunchKernelGGL(k_tr_qk, dim3(36, 4, 4),  dim3(256), 0, stream, q, k, qkT);
    hipLaunchKernelGGL(k_tr_v,  dim3(36, 4, 8),  dim3(256), 0, stream, v, vT);
    hipLaunchKernelGGL(k_w1r,   dim3(4608),      dim3(256), 0, stream, w1, w1r);
    hipLaunchKernelGGL(k_wdr,   dim3(2304),      dim3(256), 0, stream, dw, wdr);
    hipLaunchKernelGGL(k_w2r,   dim3(288),       dim3(256), 0, stream, w2, w2r);
    hipLaunchKernelGGL(k_pads,  dim3(1),         dim3(256), 0, stream, qkT);
    hipLaunchKernelGGL(k_conv1, dim3(144, 2, 3), dim3(256), 0, stream, qkT, w1r, feat3);
    hipLaunchKernelGGL(k_fcast, dim3(2305, 2),   dim3(256), 0, stream, feat3, b1, featb);
    hipLaunchKernelGGL(k_conv2, dim3(36, 2, 9),  dim3(256), 0, stream, featb, w2r, off9);
    hipLaunchKernelGGL(k_osum,  dim3(324),       dim3(256), 0, stream, off9, b2, off);
    hipLaunchKernelGGL(k_deform,dim3(72, 8),     dim3(256), 0, stream, vT, off, wdr, db, q, out);
}